// Round 6
// baseline (68.505 us; speedup 1.0000x reference)
//
#include <hip/hip_runtime.h>

// FractalEmbedding: cs[M,2] -> 8 Julia iters -> feats[M,16]
//                   out[M,D] = feats @ W^T * scale   (W is [D,16] row-major)
// M = 32768, D = 2048, fp32 out = 256 MiB -> write-BW-bound.
//
// R6: fill-isomorphic global sweep. R2-R5 proved compute structure irrelevant
// (57-62us for 4 schemes) while rocclr fill sustains 7.06 TB/s; remaining
// delta vs fill = instantaneous write-address footprint. Here ALL 1024 blocks
// are co-resident (70 VGPR, no LDS, launch_bounds(256,4)) and grid-stride the
// output: per iteration the whole chip writes ONE dense 4 MiB window (each
// wave a 1 KB contiguous segment), advancing monotonically through all
// 256 MiB -- byte-identical access pattern to fillBufferAligned.
//  - thread t owns cols (4t mod 2048)..+3 forever -> W in 32 VGPRs, scale in.
//  - row = (4t >> 11) + 512*k, wave-uniform -> cs[row] broadcast load,
//    software-pipelined one iteration ahead (latency hides under compute).

#define STEPS 8
#define KF 16
#define DDIM 2048
#define BLOCK 256
#define GRID 1024
#define ROWS_PER_STEP 512     // GRID*BLOCK*4 floats / DDIM

typedef float f32x2 __attribute__((ext_vector_type(2)));
typedef float f32x4 __attribute__((ext_vector_type(4)));

__global__ __launch_bounds__(BLOCK, 4) void fractal_embed_kernel(
    const float* __restrict__ cs,     // [M,2] interleaved (cr, ci)
    const float* __restrict__ W,      // [D,16] row-major
    const float* __restrict__ scale,  // [1]
    float* __restrict__ out,          // [M,D]
    int iters)
{
    const int g    = blockIdx.x * BLOCK + threadIdx.x;  // 0..262143
    const int col  = (4 * g) & (DDIM - 1);              // fixed column group
    const int row0 = (4 * g) >> 11;                     // 0..511

    const float s = scale[0];

    // W rows for this thread's 4 columns, scale folded in. 32 VGPRs.
    f32x2 w2[4][KF / 2];
#pragma unroll
    for (int r = 0; r < 4; ++r) {
        const f32x2* wp = reinterpret_cast<const f32x2*>(W + (size_t)(col + r) * KF);
#pragma unroll
        for (int q = 0; q < KF / 2; ++q) {
            f32x2 v = wp[q];
            v.x *= s; v.y *= s;
            w2[r][q] = v;
        }
    }

    const f32x2* cs2 = reinterpret_cast<const f32x2*>(cs);
    f32x2 c = cs2[row0];                 // wave-uniform broadcast load

#pragma unroll 1
    for (int k = 0; k < iters; ++k) {
        const int row = row0 + k * ROWS_PER_STEP;
        // Prefetch next iteration's c; latency hides under this iteration.
        f32x2 cn = c;
        if (k + 1 < iters) cn = cs2[row + ROWS_PER_STEP];

        // Julia iteration z <- z^2 + c from z=0; f2[st] = (zr, zi).
        f32x2 f2[STEPS];
        float zr = 0.0f, zi = 0.0f;
#pragma unroll
        for (int st = 0; st < STEPS; ++st) {
            const float nzr = fmaf(zr, zr, fmaf(-zi, zi, c.x));
            const float nzi = fmaf(zr + zr, zi, c.y);
            zr = nzr; zi = nzi;
            f2[st].x = zr;
            f2[st].y = zi;
        }

        // 4 dot products (length 16) via pk-fma against register W.
        f32x4 o;
#pragma unroll
        for (int r = 0; r < 4; ++r) {
            f32x2 a2 = {0.0f, 0.0f};
#pragma unroll
            for (int q = 0; q < KF / 2; ++q)
                a2 = __builtin_elementwise_fma(f2[q], w2[r][q], a2);
            o[r] = a2.x + a2.y;
        }

        // One dense 1 KB-per-wave store; whole chip sweeps one 4 MiB window.
        reinterpret_cast<f32x4*>(out + (size_t)row * DDIM + col)[0] = o;
        c = cn;
    }
}

extern "C" void kernel_launch(void* const* d_in, const int* in_sizes, int n_in,
                              void* d_out, int out_size, void* d_ws, size_t ws_size,
                              hipStream_t stream) {
    // d_in[0] = token_ids (int64, unused — cs precomputed host-side)
    // d_in[1] = cs [B,L,2] f32; d_in[2] = W [D,16] f32; d_in[3] = scale [1] f32
    const float* cs    = (const float*)d_in[1];
    const float* W     = (const float*)d_in[2];
    const float* scale = (const float*)d_in[3];
    float* out         = (float*)d_out;

    const int M = in_sizes[0];                 // B*L = 32768 rows
    const int iters = M / ROWS_PER_STEP;       // 64 sweep steps
    fractal_embed_kernel<<<GRID, BLOCK, 0, stream>>>(cs, W, scale, out, iters);
}

// Round 7
// 52.197 us; speedup vs baseline: 1.3124x; 1.3124x over previous
//
#include <hip/hip_runtime.h>

// FractalEmbedding: cs[M,2] -> 8 Julia iters -> feats[M,16]
//                   out[M,D] = feats @ W^T * scale   (W is [D,16] row-major)
// M = 32768, D = 2048, fp32 out = 256 MiB -> write-BW-bound (fill = 7 TB/s
// => 38us floor).
//
// R7: R5 structure (contiguous 512 KB slab per block, dense 1 KB wave
// stores, pk-fma dot, LDS-staged cs) with ONE block generation:
// ROWS_PER_BLK 32->64, grid 1024->512 = 2 blocks/CU, all co-resident.
// Theory: R5's ~19us over the write floor is gen-2 setup (128 KB of
// uncoalesced W reads per block) serializing mid-kernel + ramp/drain.
// Single generation pays setup once, fully overlapped across the chip.

#define STEPS 8
#define KF 16
#define DDIM 2048
#define BLOCK 256
#define CPT 8                 // columns per thread: two dense 4-col groups
#define ROWS_PER_BLK 64

typedef float f32x2 __attribute__((ext_vector_type(2)));
typedef float f32x4 __attribute__((ext_vector_type(4)));

__global__ __launch_bounds__(BLOCK, 2) void fractal_embed_kernel(
    const float* __restrict__ cs,     // [M,2] interleaved (cr, ci)
    const float* __restrict__ W,      // [D,16] row-major
    const float* __restrict__ scale,  // [1]
    float* __restrict__ out)          // [M,D]
{
    const int tid  = threadIdx.x;
    const int row0 = blockIdx.x * ROWS_PER_BLK;
    const int ca   = tid * 4;          // cols    0..1023 across the block
    const int cb   = 1024 + tid * 4;   // cols 1024..2047 across the block

    // Stage this block's 64 (cr,ci) pairs into LDS: one coalesced 512 B load.
    __shared__ float s_cs[2 * ROWS_PER_BLK];
    if (tid < 2 * ROWS_PER_BLK)
        s_cs[tid] = cs[(size_t)row0 * 2 + tid];

    const float s = scale[0];

    // W rows for this thread's 8 columns, scale folded in. 64 VGPRs.
    f32x2 w2[CPT][KF / 2];
#pragma unroll
    for (int r = 0; r < CPT; ++r) {
        const int d = (r < 4) ? (ca + r) : (cb + (r - 4));
        const f32x2* wp = reinterpret_cast<const f32x2*>(W + (size_t)d * KF);
#pragma unroll
        for (int q = 0; q < KF / 2; ++q) {
            f32x2 v = wp[q];
            v.x *= s; v.y *= s;
            w2[r][q] = v;
        }
    }
    __syncthreads();

#pragma unroll 2
    for (int rr = 0; rr < ROWS_PER_BLK; ++rr) {
        const int row = row0 + rr;
        const float cr = s_cs[2 * rr];       // wave-uniform broadcast reads
        const float ci = s_cs[2 * rr + 1];

        // Julia iteration z <- z^2 + c from z=0; f2[st] = (zr, zi).
        f32x2 f2[STEPS];
        float zr = 0.0f, zi = 0.0f;
#pragma unroll
        for (int st = 0; st < STEPS; ++st) {
            const float nzr = fmaf(zr, zr, fmaf(-zi, zi, cr));
            const float nzi = fmaf(zr + zr, zi, ci);
            zr = nzr; zi = nzi;
            f2[st].x = zr;
            f2[st].y = zi;
        }

        // 8 dot products (length 16) via pk-fma against register W.
        f32x4 oa, ob;
#pragma unroll
        for (int r = 0; r < CPT; ++r) {
            f32x2 a2 = {0.0f, 0.0f};
#pragma unroll
            for (int q = 0; q < KF / 2; ++q)
                a2 = __builtin_elementwise_fma(f2[q], w2[r][q], a2);
            const float v = a2.x + a2.y;
            if (r < 4) oa[r] = v;
            else       ob[r - 4] = v;
        }

        // Two dense 1 KB-per-wave stores; block walks a 512 KB slab row-major.
        float* rowp = out + (size_t)row * DDIM;
        reinterpret_cast<f32x4*>(rowp + ca)[0] = oa;
        reinterpret_cast<f32x4*>(rowp + cb)[0] = ob;
    }
}

extern "C" void kernel_launch(void* const* d_in, const int* in_sizes, int n_in,
                              void* d_out, int out_size, void* d_ws, size_t ws_size,
                              hipStream_t stream) {
    // d_in[0] = token_ids (int64, unused — cs precomputed host-side)
    // d_in[1] = cs [B,L,2] f32; d_in[2] = W [D,16] f32; d_in[3] = scale [1] f32
    const float* cs    = (const float*)d_in[1];
    const float* W     = (const float*)d_in[2];
    const float* scale = (const float*)d_in[3];
    float* out         = (float*)d_out;

    const int M = in_sizes[0];                 // B*L = 32768 rows
    const int grid = M / ROWS_PER_BLK;         // 512 blocks: ONE generation
    fractal_embed_kernel<<<grid, BLOCK, 0, stream>>>(cs, W, scale, out);
}